// Round 22
// baseline (288.897 us; speedup 1.0000x reference)
//
#include <hip/hip_runtime.h>
#include <hip/hip_bf16.h>

#define N_NODES 100000
#define N_EDGES 600000
#define N_REL   3
#define D_INF   256
#define D_OUTF  128
#define TOT_E   (3 * N_EDGES)

#define NB_REL   49                              // dst>>11 -> 0..48
#define NBUCKT   (3 * NB_REL)                    // 147
#define CAPB     16384                           // staging capacity per bucket

#define NPART_BLOCKS ((TOT_E + 4095) / 4096)     // 440

#define NPROJ_BLOCKS ((N_NODES + 63) / 64)              // 1563 (both W per block)
#define NTOT_BLOCKS  (NPROJ_BLOCKS + NBUCKT)            // 1710

typedef __attribute__((ext_vector_type(8))) short          bf16x8;
typedef __attribute__((ext_vector_type(8))) unsigned short ushort8;
typedef __attribute__((ext_vector_type(4))) float          f32x4;

#define LPAD 72
#define LTS  136

__device__ __forceinline__ unsigned short bf16_rne(float v) {
    unsigned int b = __float_as_uint(v);
    b += 0x7FFFu + ((b >> 16) & 1u);
    return (unsigned short)(b >> 16);
}

// ---------------------------------------------------------------------------
// K0 (FUSED): wt_prep (blocks 0..255) + bucket partition (440 blocks).
// ---------------------------------------------------------------------------
__global__ __launch_bounds__(256) void part_wt(
    const float* __restrict__ Wl, const float* __restrict__ Wr,
    unsigned short* __restrict__ wt,
    const int* __restrict__ ei, int* __restrict__ bcnt,
    uint2* __restrict__ gstage)
{
    const int bid = blockIdx.x;
    const int t   = threadIdx.x;
    if (bid < 256) {
        const int k = bid;
        const int w = t >> 7;
        const int n = t & 127;
        const float v = (w ? Wr : Wl)[(size_t)k * D_OUTF + n];
        const unsigned short h = bf16_rne(v);
        const float fhi = __uint_as_float(((unsigned int)h) << 16);
        const unsigned short g = bf16_rne(v - fhi);
        const int kb   = k >> 6;
        const int kk   = (k >> 5) & 1;
        const int lgrp = (k >> 3) & 3;
        const int j    = k & 7;
        const int cf   = n >> 4;
        const int lane = lgrp * 16 + (n & 15);
        const size_t fh = ((((size_t)(w * 2 + 0) * 4 + kb) * 2 + kk) * 8 + cf) * 512 + lane * 8 + j;
        const size_t fl = ((((size_t)(w * 2 + 1) * 4 + kb) * 2 + kk) * 8 + cf) * 512 + lane * 8 + j;
        wt[fh] = h;
        wt[fl] = g;
        return;
    }
    __shared__ int lh[NBUCKT];
    __shared__ int lc[NBUCKT];
    const int base = (bid - 256) * 4096;

    for (int q = t; q < NBUCKT; q += 256) lh[q] = 0;
    __syncthreads();
#pragma unroll
    for (int r = 0; r < 16; ++r) {
        const int ge = base + r * 256 + t;
        if (ge < TOT_E) {
            const int rr = (ge >= 2 * N_EDGES) ? 2 : ((ge >= N_EDGES) ? 1 : 0);
            const int e  = ge - rr * N_EDGES;
            const int dst = ei[(size_t)rr * 2 * N_EDGES + N_EDGES + e];
            atomicAdd(&lh[rr * NB_REL + (dst >> 11)], 1);
        }
    }
    __syncthreads();
    for (int q = t; q < NBUCKT; q += 256)
        lc[q] = lh[q] ? atomicAdd(&bcnt[q], lh[q]) : 0;
    __syncthreads();
#pragma unroll
    for (int r = 0; r < 16; ++r) {
        const int ge = base + r * 256 + t;
        if (ge < TOT_E) {
            const int rr = (ge >= 2 * N_EDGES) ? 2 : ((ge >= N_EDGES) ? 1 : 0);
            const int e  = ge - rr * N_EDGES;
            const int src = ei[(size_t)rr * 2 * N_EDGES + e];
            const int dst = ei[(size_t)rr * 2 * N_EDGES + N_EDGES + e];
            const int qb  = rr * NB_REL + (dst >> 11);
            const int off = atomicAdd(&lc[qb], 1);
            uint2 u; u.x = (unsigned)src; u.y = (unsigned)(dst | (rr << 20));
            gstage[(size_t)qb * CAPB + off] = u;
        }
    }
}

// ---------------------------------------------------------------------------
// K1 (FUSED): proj GEMM, 512 threads = 8 waves: waves 0-3 -> Wl, waves 4-7
// -> Wr.  x tile staged+converted ONCE per 64-node tile; per-wave MFMA chain
// identical to the 256-thr version (wave parallelism preserved, occupancy
// 32 waves/CU).  ∥  bucket scatter+CSR-build (512 threads).
// ---------------------------------------------------------------------------
__global__ __launch_bounds__(512, 8) void proj_scatter(
    const float* __restrict__ x, const unsigned short* __restrict__ wt,
    const float* __restrict__ bl, const float* __restrict__ br,
    const float* __restrict__ attn,
    float* __restrict__ rbuf,
    float* __restrict__ alr,  float* __restrict__ ar,
    unsigned short* __restrict__ lbf,
    const uint2* __restrict__ gstage, const int* __restrict__ bcnt,
    int* __restrict__ deg, int* __restrict__ rowst, int* __restrict__ colall)
{
    __shared__ unsigned short smem[2 * 64 * LPAD];   // 18432 B
    __shared__ int wsum2[8];
    __shared__ int wexcl2[8];

    const int bid = blockIdx.x;
    const unsigned int pb = (unsigned int)(((unsigned long long)bid * NPROJ_BLOCKS) / NTOT_BLOCKS);
    const unsigned int pa = (unsigned int)(((unsigned long long)(bid + 1) * NPROJ_BLOCKS) / NTOT_BLOCKS);

    if (pa == pb) {
        // ============ bucket scatter + CSR build (512 thr) ============
        const int b     = bid - (int)pb;          // 0..146
        const int rrb   = b / NB_REL;
        const int node0 = (b % NB_REL) * 2048;
        const int nN    = min(2048, N_NODES - node0);
        const int t     = threadIdx.x;
        int* hist = (int*)smem;                   // 2048 ints
        const int cnt_b = bcnt[b];
        const size_t sbase = (size_t)b * CAPB;

        // gb = exclusive prefix of bcnt at b (512-thread reduce)
        {
            int pv = (t < b) ? bcnt[t] : 0;       // b <= 146 < 512
#pragma unroll
            for (int m = 32; m >= 1; m >>= 1) pv += __shfl_xor(pv, m);
            if ((t & 63) == 0) wsum2[t >> 6] = pv;
        }
        for (int q = t; q < 2048; q += 512) hist[q] = 0;
        __syncthreads();
        int gb = 0;
#pragma unroll
        for (int i = 0; i < 8; ++i) gb += wsum2[i];

        for (int e = t; e < cnt_b; e += 512) {
            const uint2 u = gstage[sbase + e];
            atomicAdd(&hist[(int)(u.y & 0xFFFFFu) - node0], 1);
        }
        __syncthreads();
        for (int q = t; q < nN; q += 512)
            deg[rrb * N_NODES + node0 + q] = hist[q];
        __syncthreads();
        // in-block exclusive scan of hist[2048]: 512 thr x 4 elems
        {
            const int lane = t & 63;
            const int wid  = t >> 6;
            int v[4]; int tsum = 0;
#pragma unroll
            for (int i = 0; i < 4; ++i) { v[i] = hist[t * 4 + i]; tsum += v[i]; }
            int inc = tsum;
#pragma unroll
            for (int off2 = 1; off2 < 64; off2 <<= 1) {
                const int u2 = __shfl_up(inc, off2);
                if (lane >= off2) inc += u2;
            }
            if (lane == 63) wsum2[wid] = inc;
            __syncthreads();
            if (t == 0) {
                int s = 0;
#pragma unroll
                for (int i2 = 0; i2 < 8; ++i2) { const int tv = wsum2[i2]; wexcl2[i2] = s; s += tv; }
            }
            __syncthreads();
            int run = gb + wexcl2[wid] + (inc - tsum);
#pragma unroll
            for (int i = 0; i < 4; ++i) {
                const int q = t * 4 + i;
                const int st = run;
                run += v[i];
                hist[q] = st;
                if (q < nN) rowst[rrb * N_NODES + node0 + q] = st;
            }
        }
        __syncthreads();
        for (int e = t; e < cnt_b; e += 512) {
            const uint2 u = gstage[sbase + e];
            const int loc = (int)(u.y & 0xFFFFFu) - node0;
            const int pos = atomicAdd(&hist[loc], 1);
            colall[pos] = (int)u.x;
        }
        return;
    }

    // ================= proj block #pb (8 waves, both W) =================
    const int tid  = threadIdx.x;
    const int nb   = (int)pb * 64;

    const int lane = tid & 63;
    const int wave = tid >> 6;      // 0..7
    const int w    = wave >> 2;     // 0: Wl, 1: Wr
    const int wv   = wave & 3;      // row-quadrant within tile
    const int rowf = lane & 15;
    const int kgrp = lane >> 4;     // 0..3

    const int r_   = tid >> 3;      // staging row 0..63
    const int seg_ = tid & 7;       // staging segment (8 floats)
    int rowg = nb + r_; if (rowg >= N_NODES) rowg = N_NODES - 1;
    const float* xrow = x + (size_t)rowg * D_INF + seg_ * 8;

    f32x4 acc[8];
#pragma unroll
    for (int cf = 0; cf < 8; ++cf) acc[cf] = (f32x4){0.f, 0.f, 0.f, 0.f};

    for (int kb4 = 0; kb4 < 4; ++kb4) {
        __syncthreads();
        // ---- stage x tile (once for both W): thread -> 8 floats
        {
            const float* s = xrow + kb4 * 64;
            const float4 v0 = *reinterpret_cast<const float4*>(s);
            const float4 v1 = *reinterpret_cast<const float4*>(s + 4);
            const float vv[8] = {v0.x, v0.y, v0.z, v0.w, v1.x, v1.y, v1.z, v1.w};
            ushort8 hv, gv;
#pragma unroll
            for (int q = 0; q < 8; ++q) {
                const unsigned short h = bf16_rne(vv[q]);
                hv[q] = h;
                const float fhi = __uint_as_float(((unsigned int)h) << 16);
                gv[q] = bf16_rne(vv[q] - fhi);
            }
            *reinterpret_cast<ushort8*>(&smem[0 * 64 * LPAD + r_ * LPAD + seg_ * 8]) = hv;
            *reinterpret_cast<ushort8*>(&smem[1 * 64 * LPAD + r_ * LPAD + seg_ * 8]) = gv;
        }
        __syncthreads();

        // ---- MFMA; per-wave chain identical to 256-thr version
#pragma unroll
        for (int kk = 0; kk < 2; ++kk) {
            const int ko = kk * 32 + kgrp * 8;
            const bf16x8 ahi = *reinterpret_cast<const bf16x8*>(&smem[0 * 64 * LPAD + (wv * 16 + rowf) * LPAD + ko]);
            const bf16x8 alo = *reinterpret_cast<const bf16x8*>(&smem[1 * 64 * LPAD + (wv * 16 + rowf) * LPAD + ko]);
#pragma unroll
            for (int cf = 0; cf < 8; ++cf) {
                const bf16x8 bhi = *reinterpret_cast<const bf16x8*>(
                    wt + ((((size_t)(w * 2 + 0) * 4 + kb4) * 2 + kk) * 8 + cf) * 512 + lane * 8);
                const bf16x8 blo = *reinterpret_cast<const bf16x8*>(
                    wt + ((((size_t)(w * 2 + 1) * 4 + kb4) * 2 + kk) * 8 + cf) * 512 + lane * 8);
                acc[cf] = __builtin_amdgcn_mfma_f32_16x16x32_bf16(ahi, bhi, acc[cf], 0, 0, 0);
                acc[cf] = __builtin_amdgcn_mfma_f32_16x16x32_bf16(ahi, blo, acc[cf], 0, 0, 0);
                acc[cf] = __builtin_amdgcn_mfma_f32_16x16x32_bf16(alo, bhi, acc[cf], 0, 0, 0);
            }
        }
    }
    __syncthreads();   // xs reads done; safe to reuse smem in phase 2

    // ==== phase 2: relu + outputs ====
    float o_[8][4];
    {
        const float* bias = w ? br : bl;
#pragma unroll
        for (int cf = 0; cf < 8; ++cf) {
            const float bvv = bias[cf * 16 + rowf];
#pragma unroll
            for (int j = 0; j < 4; ++j)
                o_[cf][j] = fmaxf(acc[cf][j] + bvv, 0.f);
        }
    }

    if (w == 1) {
#pragma unroll
        for (int cf = 0; cf < 8; ++cf)
#pragma unroll
            for (int j = 0; j < 4; ++j) {
                const int node = nb + wv * 16 + kgrp * 4 + j;
                if (node < N_NODES)
                    rbuf[(size_t)node * D_OUTF + cf * 16 + rowf] = o_[cf][j];
            }
    }

    // al/ar: f32 dot with attn band + 16-lane shfl reduce (over rowf)
    {
        const int woff = w ? 32 : 0;
#pragma unroll
        for (int rr = 0; rr < 3; ++rr) {
            float pr[4][4];
#pragma unroll
            for (int hh = 0; hh < 4; ++hh) {
                const float A0 = attn[rr * 256 + hh * 64 + woff + rowf];
                const float A1 = attn[rr * 256 + hh * 64 + woff + 16 + rowf];
#pragma unroll
                for (int j = 0; j < 4; ++j)
                    pr[hh][j] = fmaf(o_[2 * hh][j], A0, o_[2 * hh + 1][j] * A1);
            }
#pragma unroll
            for (int hh = 0; hh < 4; ++hh)
#pragma unroll
                for (int j = 0; j < 4; ++j) {
#pragma unroll
                    for (int m = 8; m >= 1; m >>= 1)
                        pr[hh][j] += __shfl_xor(pr[hh][j], m);
                }
            if ((rowf >> 2) == rr) {
#pragma unroll
                for (int j = 0; j < 4; ++j) {
                    float v = pr[0][j];
#pragma unroll
                    for (int hh = 1; hh < 4; ++hh)
                        if ((rowf & 3) == hh) v = pr[hh][j];
                    const int node = nb + wv * 16 + kgrp * 4 + j;
                    if (node < N_NODES) {
                        if (w == 0)
                            alr[((size_t)rr * N_NODES + node) * 4 + (rowf & 3)] = v;
                        else
                            ar[(size_t)node * 12 + rowf] = v;
                    }
                }
            }
        }
    }

    // lbf (bf16 l copy): w=0 waves write staging; all 512 threads copy out
    if (w == 0) {
#pragma unroll
        for (int cf = 0; cf < 8; ++cf)
#pragma unroll
            for (int j = 0; j < 4; ++j)
                smem[(wv * 16 + kgrp * 4 + j) * LTS + cf * 16 + rowf] = bf16_rne(o_[cf][j]);
    }
    __syncthreads();
#pragma unroll
    for (int q = 0; q < 2; ++q) {
        const int idx = tid + q * 512;     // 0..1023 chunks of 8 us
        const int r2  = idx >> 4;
        const int c8  = (idx & 15) * 8;
        const int node = nb + r2;
        if (node < N_NODES)
            *reinterpret_cast<ushort8*>(&lbf[(size_t)node * D_OUTF + c8]) =
                *reinterpret_cast<ushort8*>(&smem[r2 * LTS + c8]);
    }
}

// ---------------------------------------------------------------------------
// K2: aggregation v6 (unchanged from R19-R21).
// ---------------------------------------------------------------------------
__global__ __launch_bounds__(256) void aggregate_kernel(
    const uint4* __restrict__ lbf128, const float* __restrict__ rbuf,
    const float* __restrict__ alr,  const float* __restrict__ ar,
    const int* __restrict__ rowst,  const int* __restrict__ deg,
    const int* __restrict__ colall,
    const float* __restrict__ rel_attn_l, const float* __restrict__ rel_attn_r,
    const float* __restrict__ rel_bias,   float* __restrict__ out)
{
    __shared__ int   src_sh[4][4][3][16];        // 3 KB
    __shared__ float w_sh[4][4][3][16][4];       // 12 KB

    const int wv   = threadIdx.x >> 6;
    const int lane = threadIdx.x & 63;
    const int g    = lane >> 4;          // node slot 0..3
    const int j    = lane & 15;          // lane within group
    const int n    = blockIdx.x * 16 + wv * 4 + g;

    const int h  = j >> 2;               // head 0..3 (4 lanes per head)
    const int c8 = j * 8;                // first of 8 owned channels

    int   start_[3], cnt_[3], cm_[3], base_[3];
    float4 ar4_[3];
#pragma unroll
    for (int rr = 0; rr < 3; ++rr) {
        start_[rr] = rowst[rr * N_NODES + n];
        cnt_[rr]   = deg[rr * N_NODES + n];
        ar4_[rr]   = *reinterpret_cast<const float4*>(ar + (size_t)n * 12 + rr * 4);
        int cm = cnt_[rr];
        cm = max(cm, __shfl_xor(cm, 16));
        cm = max(cm, __shfl_xor(cm, 32));
        cm_[rr] = cm;                    // wave-uniform
        base_[rr] = 0;
    }

    float ex[3][8];
    float den[3];
#pragma unroll
    for (int rr = 0; rr < 3; ++rr) {
        den[rr] = 0.f;
#pragma unroll
        for (int c = 0; c < 8; ++c) ex[rr][c] = 0.f;
    }

    while (base_[0] < cm_[0] || base_[1] < cm_[1] || base_[2] < cm_[2]) {
        int mm_[3];
        int mxw_[3];
#pragma unroll
        for (int rr = 0; rr < 3; ++rr) {
            mm_[rr] = 0; mxw_[rr] = 0;
            if (base_[rr] < cm_[rr]) {
                mm_[rr]  = min(16, max(0, cnt_[rr] - base_[rr]));
                mxw_[rr] = min(16, cm_[rr] - base_[rr]);
                const int sj = (j < mm_[rr]) ? colall[start_[rr] + base_[rr] + j] : 0;
                const float4 al4 = *reinterpret_cast<const float4*>(
                    alr + ((size_t)rr * N_NODES + sj) * 4);
                float t0 = al4.x + ar4_[rr].x, t1 = al4.y + ar4_[rr].y;
                float t2 = al4.z + ar4_[rr].z, t3 = al4.w + ar4_[rr].w;
                t0 = fmaxf(t0, 0.2f * t0); t1 = fmaxf(t1, 0.2f * t1);
                t2 = fmaxf(t2, 0.2f * t2); t3 = fmaxf(t3, 0.2f * t3);
                float e0 = __expf(t0), e1 = __expf(t1);
                float e2 = __expf(t2), e3 = __expf(t3);
                if (j >= mm_[rr]) { e0 = 0.f; e1 = 0.f; e2 = 0.f; e3 = 0.f; }
                src_sh[wv][g][rr][j] = sj;
                f32x4 w4; w4[0] = e0; w4[1] = e1; w4[2] = e2; w4[3] = e3;
                *reinterpret_cast<f32x4*>(&w_sh[wv][g][rr][j][0]) = w4;
            }
        }
        const int mxall = max(mxw_[0], max(mxw_[1], mxw_[2]));
        for (int i = 0; i < mxall; ++i) {
#pragma unroll
            for (int rr = 0; rr < 3; ++rr) {
                if (i < mm_[rr]) {
                    const int   srcI = src_sh[wv][g][rr][i];
                    const float wsel = w_sh[wv][g][rr][i][h];
                    const uint4 u = lbf128[(size_t)srcI * 16 + j];
                    den[rr] += wsel;
                    ex[rr][0] = fmaf(wsel, __uint_as_float(u.x << 16),         ex[rr][0]);
                    ex[rr][1] = fmaf(wsel, __uint_as_float(u.x & 0xFFFF0000u), ex[rr][1]);
                    ex[rr][2] = fmaf(wsel, __uint_as_float(u.y << 16),         ex[rr][2]);
                    ex[rr][3] = fmaf(wsel, __uint_as_float(u.y & 0xFFFF0000u), ex[rr][3]);
                    ex[rr][4] = fmaf(wsel, __uint_as_float(u.z << 16),         ex[rr][4]);
                    ex[rr][5] = fmaf(wsel, __uint_as_float(u.z & 0xFFFF0000u), ex[rr][5]);
                    ex[rr][6] = fmaf(wsel, __uint_as_float(u.w << 16),         ex[rr][6]);
                    ex[rr][7] = fmaf(wsel, __uint_as_float(u.w & 0xFFFF0000u), ex[rr][7]);
                }
            }
        }
#pragma unroll
        for (int rr = 0; rr < 3; ++rr) base_[rr] += 16;
    }

    float e[4][8];
#pragma unroll
    for (int rr = 0; rr < 3; ++rr) {
        const float inv = 1.f / (den[rr] + 1e-16f);
#pragma unroll
        for (int c = 0; c < 8; ++c) e[rr][c] = ex[rr][c] * inv;
    }
    {
        const uint4 u = lbf128[(size_t)n * 16 + j];
        e[3][0] = __uint_as_float(u.x << 16);
        e[3][1] = __uint_as_float(u.x & 0xFFFF0000u);
        e[3][2] = __uint_as_float(u.y << 16);
        e[3][3] = __uint_as_float(u.y & 0xFFFF0000u);
        e[3][4] = __uint_as_float(u.z << 16);
        e[3][5] = __uint_as_float(u.z & 0xFFFF0000u);
        e[3][6] = __uint_as_float(u.w << 16);
        e[3][7] = __uint_as_float(u.w & 0xFFFF0000u);
    }

    float blc[8];
    {
        const float4 rva = *reinterpret_cast<const float4*>(rbuf + (size_t)n * D_OUTF + c8);
        const float4 rvb = *reinterpret_cast<const float4*>(rbuf + (size_t)n * D_OUTF + c8 + 4);
        const float4 rla = *reinterpret_cast<const float4*>(rel_attn_l + c8);
        const float4 rlb = *reinterpret_cast<const float4*>(rel_attn_l + c8 + 4);
        blc[0] = fmaxf(rva.x * rla.x, 0.f);
        blc[1] = fmaxf(rva.y * rla.y, 0.f);
        blc[2] = fmaxf(rva.z * rla.z, 0.f);
        blc[3] = fmaxf(rva.w * rla.w, 0.f);
        blc[4] = fmaxf(rvb.x * rlb.x, 0.f);
        blc[5] = fmaxf(rvb.y * rlb.y, 0.f);
        blc[6] = fmaxf(rvb.z * rlb.z, 0.f);
        blc[7] = fmaxf(rvb.w * rlb.w, 0.f);
    }

    float beta[4];
#pragma unroll
    for (int s = 0; s < 4; ++s) {
        const float4 ra = *reinterpret_cast<const float4*>(rel_attn_r + s * D_OUTF + c8);
        const float4 rb = *reinterpret_cast<const float4*>(rel_attn_r + s * D_OUTF + c8 + 4);
        float p = 0.f;
        p = fmaf(blc[0], fmaxf(e[s][0] * ra.x, 0.f), p);
        p = fmaf(blc[1], fmaxf(e[s][1] * ra.y, 0.f), p);
        p = fmaf(blc[2], fmaxf(e[s][2] * ra.z, 0.f), p);
        p = fmaf(blc[3], fmaxf(e[s][3] * ra.w, 0.f), p);
        p = fmaf(blc[4], fmaxf(e[s][4] * rb.x, 0.f), p);
        p = fmaf(blc[5], fmaxf(e[s][5] * rb.y, 0.f), p);
        p = fmaf(blc[6], fmaxf(e[s][6] * rb.z, 0.f), p);
        p = fmaf(blc[7], fmaxf(e[s][7] * rb.w, 0.f), p);
        p += __shfl_xor(p, 2);
        p += __shfl_xor(p, 1);
        beta[s] = p + rel_bias[s];
    }

    const float mx2 = fmaxf(fmaxf(beta[0], beta[1]), fmaxf(beta[2], beta[3]));
    float ssum = 0.f;
#pragma unroll
    for (int s = 0; s < 4; ++s) { beta[s] = __expf(beta[s] - mx2); ssum += beta[s]; }
    const float isum = 1.f / ssum;
    float o[8];
#pragma unroll
    for (int c = 0; c < 8; ++c) o[c] = 0.f;
#pragma unroll
    for (int s = 0; s < 4; ++s) {
        const float b = beta[s] * isum;
#pragma unroll
        for (int c = 0; c < 8; ++c) o[c] = fmaf(e[s][c], b, o[c]);
    }
    float4 ova, ovb;
    ova.x = fmaxf(o[0], 0.f); ova.y = fmaxf(o[1], 0.f);
    ova.z = fmaxf(o[2], 0.f); ova.w = fmaxf(o[3], 0.f);
    ovb.x = fmaxf(o[4], 0.f); ovb.y = fmaxf(o[5], 0.f);
    ovb.z = fmaxf(o[6], 0.f); ovb.w = fmaxf(o[7], 0.f);
    *reinterpret_cast<float4*>(out + (size_t)n * D_OUTF + c8)     = ova;
    *reinterpret_cast<float4*>(out + (size_t)n * D_OUTF + c8 + 4) = ovb;
}

// ---------------------------------------------------------------------------
extern "C" void kernel_launch(void* const* d_in, const int* in_sizes, int n_in,
                              void* d_out, int out_size, void* d_ws, size_t ws_size,
                              hipStream_t stream)
{
    const float* x     = (const float*)d_in[0];
    const int*   ei    = (const int*)  d_in[1];
    const float* Wl    = (const float*)d_in[2];
    const float* bl    = (const float*)d_in[3];
    const float* Wr    = (const float*)d_in[4];
    const float* br    = (const float*)d_in[5];
    const float* attn  = (const float*)d_in[6];
    const float* ral   = (const float*)d_in[7];
    const float* rar   = (const float*)d_in[8];
    const float* rbias = (const float*)d_in[9];
    float* out = (float*)d_out;

    char* ws = (char*)d_ws;
    size_t off = 0;
    float* rbuf   = (float*)(ws + off); off += (size_t)N_NODES * D_OUTF * 4;    // 51.2 MB
    float* alr    = (float*)(ws + off); off += (size_t)3 * N_NODES * 4 * 4;     // 4.8 MB
    float* ar     = (float*)(ws + off); off += (size_t)N_NODES * 12 * 4;        // 4.8 MB
    int*   deg    = (int*)  (ws + off); off += (size_t)3 * N_NODES * 4;         // 1.2 MB
    int*   rowst  = (int*)  (ws + off); off += (size_t)3 * N_NODES * 4;         // 1.2 MB
    int*   colall = (int*)  (ws + off); off += (size_t)TOT_E * 4;               // 7.2 MB
    int*   bcnt   = (int*)  (ws + off); off += (size_t)256 * 4;
    unsigned short* wt  = (unsigned short*)(ws + off); off += (size_t)2 * 2 * 128 * 256 * 2; // 256 KB
    unsigned short* lbf = (unsigned short*)(ws + off); off += (size_t)N_NODES * D_OUTF * 2;  // 25.6 MB
    uint2* gstage = (uint2*)(ws + off); off += (size_t)NBUCKT * CAPB * 8;       // 19.3 MB

    hipMemsetAsync(bcnt, 0, (size_t)NBUCKT * 4, stream);

    part_wt<<<256 + NPART_BLOCKS, 256, 0, stream>>>(Wl, Wr, wt, ei, bcnt, gstage);

    // fused: proj (8-wave, x staged once) ∥ bucket scatter + CSR build
    proj_scatter<<<NTOT_BLOCKS, 512, 0, stream>>>(
        x, wt, bl, br, attn, rbuf, alr, ar, lbf, gstage, bcnt,
        deg, rowst, colall);

    aggregate_kernel<<<N_NODES / 16, 256, 0, stream>>>(
        (const uint4*)lbf, rbuf, alr, ar, rowst, deg, colall,
        ral, rar, rbias, out);
}

// Round 23
// 276.084 us; speedup vs baseline: 1.0464x; 1.0464x over previous
//
#include <hip/hip_runtime.h>
#include <hip/hip_bf16.h>

#define N_NODES 100000
#define N_EDGES 600000
#define N_REL   3
#define D_INF   256
#define D_OUTF  128
#define TOT_E   (3 * N_EDGES)

#define NB_REL   49                              // dst>>11 -> 0..48
#define NBUCKT   (3 * NB_REL)                    // 147
#define CAPB     16384                           // staging capacity per bucket

#define NPART_BLOCKS ((TOT_E + 4095) / 4096)     // 440

#define NPROJ_BLOCKS ((N_NODES + 63) / 64)              // 1563 (both W per block)
#define NTOT_BLOCKS  (NPROJ_BLOCKS + NBUCKT)            // 1710

typedef __attribute__((ext_vector_type(8))) short          bf16x8;
typedef __attribute__((ext_vector_type(8))) unsigned short ushort8;
typedef __attribute__((ext_vector_type(4))) float          f32x4;

#define LPAD 72
#define LTS  136

__device__ __forceinline__ unsigned short bf16_rne(float v) {
    unsigned int b = __float_as_uint(v);
    b += 0x7FFFu + ((b >> 16) & 1u);
    return (unsigned short)(b >> 16);
}

// ---------------------------------------------------------------------------
// K0 (FUSED): wt_prep (blocks 0..255) + bucket partition (440 blocks).
// ---------------------------------------------------------------------------
__global__ __launch_bounds__(256) void part_wt(
    const float* __restrict__ Wl, const float* __restrict__ Wr,
    unsigned short* __restrict__ wt,
    const int* __restrict__ ei, int* __restrict__ bcnt,
    uint2* __restrict__ gstage)
{
    const int bid = blockIdx.x;
    const int t   = threadIdx.x;
    if (bid < 256) {
        const int k = bid;
        const int w = t >> 7;
        const int n = t & 127;
        const float v = (w ? Wr : Wl)[(size_t)k * D_OUTF + n];
        const unsigned short h = bf16_rne(v);
        const float fhi = __uint_as_float(((unsigned int)h) << 16);
        const unsigned short g = bf16_rne(v - fhi);
        const int kb   = k >> 6;
        const int kk   = (k >> 5) & 1;
        const int lgrp = (k >> 3) & 3;
        const int j    = k & 7;
        const int cf   = n >> 4;
        const int lane = lgrp * 16 + (n & 15);
        const size_t fh = ((((size_t)(w * 2 + 0) * 4 + kb) * 2 + kk) * 8 + cf) * 512 + lane * 8 + j;
        const size_t fl = ((((size_t)(w * 2 + 1) * 4 + kb) * 2 + kk) * 8 + cf) * 512 + lane * 8 + j;
        wt[fh] = h;
        wt[fl] = g;
        return;
    }
    __shared__ int lh[NBUCKT];
    __shared__ int lc[NBUCKT];
    const int base = (bid - 256) * 4096;

    for (int q = t; q < NBUCKT; q += 256) lh[q] = 0;
    __syncthreads();
#pragma unroll
    for (int r = 0; r < 16; ++r) {
        const int ge = base + r * 256 + t;
        if (ge < TOT_E) {
            const int rr = (ge >= 2 * N_EDGES) ? 2 : ((ge >= N_EDGES) ? 1 : 0);
            const int e  = ge - rr * N_EDGES;
            const int dst = ei[(size_t)rr * 2 * N_EDGES + N_EDGES + e];
            atomicAdd(&lh[rr * NB_REL + (dst >> 11)], 1);
        }
    }
    __syncthreads();
    for (int q = t; q < NBUCKT; q += 256)
        lc[q] = lh[q] ? atomicAdd(&bcnt[q], lh[q]) : 0;
    __syncthreads();
#pragma unroll
    for (int r = 0; r < 16; ++r) {
        const int ge = base + r * 256 + t;
        if (ge < TOT_E) {
            const int rr = (ge >= 2 * N_EDGES) ? 2 : ((ge >= N_EDGES) ? 1 : 0);
            const int e  = ge - rr * N_EDGES;
            const int src = ei[(size_t)rr * 2 * N_EDGES + e];
            const int dst = ei[(size_t)rr * 2 * N_EDGES + N_EDGES + e];
            const int qb  = rr * NB_REL + (dst >> 11);
            const int off = atomicAdd(&lc[qb], 1);
            uint2 u; u.x = (unsigned)src; u.y = (unsigned)(dst | (rr << 20));
            gstage[(size_t)qb * CAPB + off] = u;
        }
    }
}

// ---------------------------------------------------------------------------
// K1 (FUSED): proj GEMM, 512 threads = 8 waves: waves 0-3 -> Wl, waves 4-7
// -> Wr.  x staged+converted ONCE; per-wave MFMA chain identical to the
// 256-thr version.  launch_bounds(512,4): VGPR cap 64 (holds ~40, NO SPILL),
// 32 waves/CU.  ∥  bucket scatter+CSR-build (512 threads).
// ---------------------------------------------------------------------------
__global__ __launch_bounds__(512, 4) void proj_scatter(
    const float* __restrict__ x, const unsigned short* __restrict__ wt,
    const float* __restrict__ bl, const float* __restrict__ br,
    const float* __restrict__ attn,
    float* __restrict__ rbuf,
    float* __restrict__ alr,  float* __restrict__ ar,
    unsigned short* __restrict__ lbf,
    const uint2* __restrict__ gstage, const int* __restrict__ bcnt,
    int* __restrict__ deg, int* __restrict__ rowst, int* __restrict__ colall)
{
    __shared__ unsigned short smem[2 * 64 * LPAD];   // 18432 B
    __shared__ int wsum2[8];
    __shared__ int wexcl2[8];

    const int bid = blockIdx.x;
    const unsigned int pb = (unsigned int)(((unsigned long long)bid * NPROJ_BLOCKS) / NTOT_BLOCKS);
    const unsigned int pa = (unsigned int)(((unsigned long long)(bid + 1) * NPROJ_BLOCKS) / NTOT_BLOCKS);

    if (pa == pb) {
        // ============ bucket scatter + CSR build (512 thr) ============
        const int b     = bid - (int)pb;          // 0..146
        const int rrb   = b / NB_REL;
        const int node0 = (b % NB_REL) * 2048;
        const int nN    = min(2048, N_NODES - node0);
        const int t     = threadIdx.x;
        int* hist = (int*)smem;                   // 2048 ints
        const int cnt_b = bcnt[b];
        const size_t sbase = (size_t)b * CAPB;

        // gb = exclusive prefix of bcnt at b (512-thread reduce)
        {
            int pv = (t < b) ? bcnt[t] : 0;       // b <= 146 < 512
#pragma unroll
            for (int m = 32; m >= 1; m >>= 1) pv += __shfl_xor(pv, m);
            if ((t & 63) == 0) wsum2[t >> 6] = pv;
        }
        for (int q = t; q < 2048; q += 512) hist[q] = 0;
        __syncthreads();
        int gb = 0;
#pragma unroll
        for (int i = 0; i < 8; ++i) gb += wsum2[i];

        for (int e = t; e < cnt_b; e += 512) {
            const uint2 u = gstage[sbase + e];
            atomicAdd(&hist[(int)(u.y & 0xFFFFFu) - node0], 1);
        }
        __syncthreads();
        for (int q = t; q < nN; q += 512)
            deg[rrb * N_NODES + node0 + q] = hist[q];
        __syncthreads();
        // in-block exclusive scan of hist[2048]: 512 thr x 4 elems
        {
            const int lane = t & 63;
            const int wid  = t >> 6;
            int v[4]; int tsum = 0;
#pragma unroll
            for (int i = 0; i < 4; ++i) { v[i] = hist[t * 4 + i]; tsum += v[i]; }
            int inc = tsum;
#pragma unroll
            for (int off2 = 1; off2 < 64; off2 <<= 1) {
                const int u2 = __shfl_up(inc, off2);
                if (lane >= off2) inc += u2;
            }
            if (lane == 63) wsum2[wid] = inc;
            __syncthreads();
            if (t == 0) {
                int s = 0;
#pragma unroll
                for (int i2 = 0; i2 < 8; ++i2) { const int tv = wsum2[i2]; wexcl2[i2] = s; s += tv; }
            }
            __syncthreads();
            int run = gb + wexcl2[wid] + (inc - tsum);
#pragma unroll
            for (int i = 0; i < 4; ++i) {
                const int q = t * 4 + i;
                const int st = run;
                run += v[i];
                hist[q] = st;
                if (q < nN) rowst[rrb * N_NODES + node0 + q] = st;
            }
        }
        __syncthreads();
        for (int e = t; e < cnt_b; e += 512) {
            const uint2 u = gstage[sbase + e];
            const int loc = (int)(u.y & 0xFFFFFu) - node0;
            const int pos = atomicAdd(&hist[loc], 1);
            colall[pos] = (int)u.x;
        }
        return;
    }

    // ================= proj block #pb (8 waves, both W) =================
    const int tid  = threadIdx.x;
    const int nb   = (int)pb * 64;

    const int lane = tid & 63;
    const int wave = tid >> 6;      // 0..7
    const int w    = wave >> 2;     // 0: Wl, 1: Wr
    const int wv   = wave & 3;      // row-quadrant within tile
    const int rowf = lane & 15;
    const int kgrp = lane >> 4;     // 0..3

    const int r_   = tid >> 3;      // staging row 0..63
    const int seg_ = tid & 7;       // staging segment (8 floats)
    int rowg = nb + r_; if (rowg >= N_NODES) rowg = N_NODES - 1;
    const float* xrow = x + (size_t)rowg * D_INF + seg_ * 8;

    f32x4 acc[8];
#pragma unroll
    for (int cf = 0; cf < 8; ++cf) acc[cf] = (f32x4){0.f, 0.f, 0.f, 0.f};

    for (int kb4 = 0; kb4 < 4; ++kb4) {
        __syncthreads();
        // ---- stage x tile (once for both W): thread -> 8 floats
        {
            const float* s = xrow + kb4 * 64;
            const float4 v0 = *reinterpret_cast<const float4*>(s);
            const float4 v1 = *reinterpret_cast<const float4*>(s + 4);
            const float vv[8] = {v0.x, v0.y, v0.z, v0.w, v1.x, v1.y, v1.z, v1.w};
            ushort8 hv, gv;
#pragma unroll
            for (int q = 0; q < 8; ++q) {
                const unsigned short h = bf16_rne(vv[q]);
                hv[q] = h;
                const float fhi = __uint_as_float(((unsigned int)h) << 16);
                gv[q] = bf16_rne(vv[q] - fhi);
            }
            *reinterpret_cast<ushort8*>(&smem[0 * 64 * LPAD + r_ * LPAD + seg_ * 8]) = hv;
            *reinterpret_cast<ushort8*>(&smem[1 * 64 * LPAD + r_ * LPAD + seg_ * 8]) = gv;
        }
        __syncthreads();

        // ---- MFMA; per-wave chain identical to 256-thr version
#pragma unroll
        for (int kk = 0; kk < 2; ++kk) {
            const int ko = kk * 32 + kgrp * 8;
            const bf16x8 ahi = *reinterpret_cast<const bf16x8*>(&smem[0 * 64 * LPAD + (wv * 16 + rowf) * LPAD + ko]);
            const bf16x8 alo = *reinterpret_cast<const bf16x8*>(&smem[1 * 64 * LPAD + (wv * 16 + rowf) * LPAD + ko]);
#pragma unroll
            for (int cf = 0; cf < 8; ++cf) {
                const bf16x8 bhi = *reinterpret_cast<const bf16x8*>(
                    wt + ((((size_t)(w * 2 + 0) * 4 + kb4) * 2 + kk) * 8 + cf) * 512 + lane * 8);
                const bf16x8 blo = *reinterpret_cast<const bf16x8*>(
                    wt + ((((size_t)(w * 2 + 1) * 4 + kb4) * 2 + kk) * 8 + cf) * 512 + lane * 8);
                acc[cf] = __builtin_amdgcn_mfma_f32_16x16x32_bf16(ahi, bhi, acc[cf], 0, 0, 0);
                acc[cf] = __builtin_amdgcn_mfma_f32_16x16x32_bf16(ahi, blo, acc[cf], 0, 0, 0);
                acc[cf] = __builtin_amdgcn_mfma_f32_16x16x32_bf16(alo, bhi, acc[cf], 0, 0, 0);
            }
        }
    }
    __syncthreads();   // xs reads done; safe to reuse smem in phase 2

    // ==== phase 2: relu + outputs ====
    float o_[8][4];
    {
        const float* bias = w ? br : bl;
#pragma unroll
        for (int cf = 0; cf < 8; ++cf) {
            const float bvv = bias[cf * 16 + rowf];
#pragma unroll
            for (int j = 0; j < 4; ++j)
                o_[cf][j] = fmaxf(acc[cf][j] + bvv, 0.f);
        }
    }

    if (w == 1) {
#pragma unroll
        for (int cf = 0; cf < 8; ++cf)
#pragma unroll
            for (int j = 0; j < 4; ++j) {
                const int node = nb + wv * 16 + kgrp * 4 + j;
                if (node < N_NODES)
                    rbuf[(size_t)node * D_OUTF + cf * 16 + rowf] = o_[cf][j];
            }
    }

    // al/ar: f32 dot with attn band + 16-lane shfl reduce (over rowf)
    {
        const int woff = w ? 32 : 0;
#pragma unroll
        for (int rr = 0; rr < 3; ++rr) {
            float pr[4][4];
#pragma unroll
            for (int hh = 0; hh < 4; ++hh) {
                const float A0 = attn[rr * 256 + hh * 64 + woff + rowf];
                const float A1 = attn[rr * 256 + hh * 64 + woff + 16 + rowf];
#pragma unroll
                for (int j = 0; j < 4; ++j)
                    pr[hh][j] = fmaf(o_[2 * hh][j], A0, o_[2 * hh + 1][j] * A1);
            }
#pragma unroll
            for (int hh = 0; hh < 4; ++hh)
#pragma unroll
                for (int j = 0; j < 4; ++j) {
#pragma unroll
                    for (int m = 8; m >= 1; m >>= 1)
                        pr[hh][j] += __shfl_xor(pr[hh][j], m);
                }
            if ((rowf >> 2) == rr) {
#pragma unroll
                for (int j = 0; j < 4; ++j) {
                    float v = pr[0][j];
#pragma unroll
                    for (int hh = 1; hh < 4; ++hh)
                        if ((rowf & 3) == hh) v = pr[hh][j];
                    const int node = nb + wv * 16 + kgrp * 4 + j;
                    if (node < N_NODES) {
                        if (w == 0)
                            alr[((size_t)rr * N_NODES + node) * 4 + (rowf & 3)] = v;
                        else
                            ar[(size_t)node * 12 + rowf] = v;
                    }
                }
            }
        }
    }

    // lbf (bf16 l copy): w=0 waves write staging; all 512 threads copy out
    if (w == 0) {
#pragma unroll
        for (int cf = 0; cf < 8; ++cf)
#pragma unroll
            for (int j = 0; j < 4; ++j)
                smem[(wv * 16 + kgrp * 4 + j) * LTS + cf * 16 + rowf] = bf16_rne(o_[cf][j]);
    }
    __syncthreads();
#pragma unroll
    for (int q = 0; q < 2; ++q) {
        const int idx = tid + q * 512;     // 0..1023 chunks of 8 us
        const int r2  = idx >> 4;
        const int c8  = (idx & 15) * 8;
        const int node = nb + r2;
        if (node < N_NODES)
            *reinterpret_cast<ushort8*>(&lbf[(size_t)node * D_OUTF + c8]) =
                *reinterpret_cast<ushort8*>(&smem[r2 * LTS + c8]);
    }
}

// ---------------------------------------------------------------------------
// K2: aggregation v6 (unchanged from R19-R21).
// ---------------------------------------------------------------------------
__global__ __launch_bounds__(256) void aggregate_kernel(
    const uint4* __restrict__ lbf128, const float* __restrict__ rbuf,
    const float* __restrict__ alr,  const float* __restrict__ ar,
    const int* __restrict__ rowst,  const int* __restrict__ deg,
    const int* __restrict__ colall,
    const float* __restrict__ rel_attn_l, const float* __restrict__ rel_attn_r,
    const float* __restrict__ rel_bias,   float* __restrict__ out)
{
    __shared__ int   src_sh[4][4][3][16];        // 3 KB
    __shared__ float w_sh[4][4][3][16][4];       // 12 KB

    const int wv   = threadIdx.x >> 6;
    const int lane = threadIdx.x & 63;
    const int g    = lane >> 4;          // node slot 0..3
    const int j    = lane & 15;          // lane within group
    const int n    = blockIdx.x * 16 + wv * 4 + g;

    const int h  = j >> 2;               // head 0..3 (4 lanes per head)
    const int c8 = j * 8;                // first of 8 owned channels

    int   start_[3], cnt_[3], cm_[3], base_[3];
    float4 ar4_[3];
#pragma unroll
    for (int rr = 0; rr < 3; ++rr) {
        start_[rr] = rowst[rr * N_NODES + n];
        cnt_[rr]   = deg[rr * N_NODES + n];
        ar4_[rr]   = *reinterpret_cast<const float4*>(ar + (size_t)n * 12 + rr * 4);
        int cm = cnt_[rr];
        cm = max(cm, __shfl_xor(cm, 16));
        cm = max(cm, __shfl_xor(cm, 32));
        cm_[rr] = cm;                    // wave-uniform
        base_[rr] = 0;
    }

    float ex[3][8];
    float den[3];
#pragma unroll
    for (int rr = 0; rr < 3; ++rr) {
        den[rr] = 0.f;
#pragma unroll
        for (int c = 0; c < 8; ++c) ex[rr][c] = 0.f;
    }

    while (base_[0] < cm_[0] || base_[1] < cm_[1] || base_[2] < cm_[2]) {
        int mm_[3];
        int mxw_[3];
#pragma unroll
        for (int rr = 0; rr < 3; ++rr) {
            mm_[rr] = 0; mxw_[rr] = 0;
            if (base_[rr] < cm_[rr]) {
                mm_[rr]  = min(16, max(0, cnt_[rr] - base_[rr]));
                mxw_[rr] = min(16, cm_[rr] - base_[rr]);
                const int sj = (j < mm_[rr]) ? colall[start_[rr] + base_[rr] + j] : 0;
                const float4 al4 = *reinterpret_cast<const float4*>(
                    alr + ((size_t)rr * N_NODES + sj) * 4);
                float t0 = al4.x + ar4_[rr].x, t1 = al4.y + ar4_[rr].y;
                float t2 = al4.z + ar4_[rr].z, t3 = al4.w + ar4_[rr].w;
                t0 = fmaxf(t0, 0.2f * t0); t1 = fmaxf(t1, 0.2f * t1);
                t2 = fmaxf(t2, 0.2f * t2); t3 = fmaxf(t3, 0.2f * t3);
                float e0 = __expf(t0), e1 = __expf(t1);
                float e2 = __expf(t2), e3 = __expf(t3);
                if (j >= mm_[rr]) { e0 = 0.f; e1 = 0.f; e2 = 0.f; e3 = 0.f; }
                src_sh[wv][g][rr][j] = sj;
                f32x4 w4; w4[0] = e0; w4[1] = e1; w4[2] = e2; w4[3] = e3;
                *reinterpret_cast<f32x4*>(&w_sh[wv][g][rr][j][0]) = w4;
            }
        }
        const int mxall = max(mxw_[0], max(mxw_[1], mxw_[2]));
        for (int i = 0; i < mxall; ++i) {
#pragma unroll
            for (int rr = 0; rr < 3; ++rr) {
                if (i < mm_[rr]) {
                    const int   srcI = src_sh[wv][g][rr][i];
                    const float wsel = w_sh[wv][g][rr][i][h];
                    const uint4 u = lbf128[(size_t)srcI * 16 + j];
                    den[rr] += wsel;
                    ex[rr][0] = fmaf(wsel, __uint_as_float(u.x << 16),         ex[rr][0]);
                    ex[rr][1] = fmaf(wsel, __uint_as_float(u.x & 0xFFFF0000u), ex[rr][1]);
                    ex[rr][2] = fmaf(wsel, __uint_as_float(u.y << 16),         ex[rr][2]);
                    ex[rr][3] = fmaf(wsel, __uint_as_float(u.y & 0xFFFF0000u), ex[rr][3]);
                    ex[rr][4] = fmaf(wsel, __uint_as_float(u.z << 16),         ex[rr][4]);
                    ex[rr][5] = fmaf(wsel, __uint_as_float(u.z & 0xFFFF0000u), ex[rr][5]);
                    ex[rr][6] = fmaf(wsel, __uint_as_float(u.w << 16),         ex[rr][6]);
                    ex[rr][7] = fmaf(wsel, __uint_as_float(u.w & 0xFFFF0000u), ex[rr][7]);
                }
            }
        }
#pragma unroll
        for (int rr = 0; rr < 3; ++rr) base_[rr] += 16;
    }

    float e[4][8];
#pragma unroll
    for (int rr = 0; rr < 3; ++rr) {
        const float inv = 1.f / (den[rr] + 1e-16f);
#pragma unroll
        for (int c = 0; c < 8; ++c) e[rr][c] = ex[rr][c] * inv;
    }
    {
        const uint4 u = lbf128[(size_t)n * 16 + j];
        e[3][0] = __uint_as_float(u.x << 16);
        e[3][1] = __uint_as_float(u.x & 0xFFFF0000u);
        e[3][2] = __uint_as_float(u.y << 16);
        e[3][3] = __uint_as_float(u.y & 0xFFFF0000u);
        e[3][4] = __uint_as_float(u.z << 16);
        e[3][5] = __uint_as_float(u.z & 0xFFFF0000u);
        e[3][6] = __uint_as_float(u.w << 16);
        e[3][7] = __uint_as_float(u.w & 0xFFFF0000u);
    }

    float blc[8];
    {
        const float4 rva = *reinterpret_cast<const float4*>(rbuf + (size_t)n * D_OUTF + c8);
        const float4 rvb = *reinterpret_cast<const float4*>(rbuf + (size_t)n * D_OUTF + c8 + 4);
        const float4 rla = *reinterpret_cast<const float4*>(rel_attn_l + c8);
        const float4 rlb = *reinterpret_cast<const float4*>(rel_attn_l + c8 + 4);
        blc[0] = fmaxf(rva.x * rla.x, 0.f);
        blc[1] = fmaxf(rva.y * rla.y, 0.f);
        blc[2] = fmaxf(rva.z * rla.z, 0.f);
        blc[3] = fmaxf(rva.w * rla.w, 0.f);
        blc[4] = fmaxf(rvb.x * rlb.x, 0.f);
        blc[5] = fmaxf(rvb.y * rlb.y, 0.f);
        blc[6] = fmaxf(rvb.z * rlb.z, 0.f);
        blc[7] = fmaxf(rvb.w * rlb.w, 0.f);
    }

    float beta[4];
#pragma unroll
    for (int s = 0; s < 4; ++s) {
        const float4 ra = *reinterpret_cast<const float4*>(rel_attn_r + s * D_OUTF + c8);
        const float4 rb = *reinterpret_cast<const float4*>(rel_attn_r + s * D_OUTF + c8 + 4);
        float p = 0.f;
        p = fmaf(blc[0], fmaxf(e[s][0] * ra.x, 0.f), p);
        p = fmaf(blc[1], fmaxf(e[s][1] * ra.y, 0.f), p);
        p = fmaf(blc[2], fmaxf(e[s][2] * ra.z, 0.f), p);
        p = fmaf(blc[3], fmaxf(e[s][3] * ra.w, 0.f), p);
        p = fmaf(blc[4], fmaxf(e[s][4] * rb.x, 0.f), p);
        p = fmaf(blc[5], fmaxf(e[s][5] * rb.y, 0.f), p);
        p = fmaf(blc[6], fmaxf(e[s][6] * rb.z, 0.f), p);
        p = fmaf(blc[7], fmaxf(e[s][7] * rb.w, 0.f), p);
        p += __shfl_xor(p, 2);
        p += __shfl_xor(p, 1);
        beta[s] = p + rel_bias[s];
    }

    const float mx2 = fmaxf(fmaxf(beta[0], beta[1]), fmaxf(beta[2], beta[3]));
    float ssum = 0.f;
#pragma unroll
    for (int s = 0; s < 4; ++s) { beta[s] = __expf(beta[s] - mx2); ssum += beta[s]; }
    const float isum = 1.f / ssum;
    float o[8];
#pragma unroll
    for (int c = 0; c < 8; ++c) o[c] = 0.f;
#pragma unroll
    for (int s = 0; s < 4; ++s) {
        const float b = beta[s] * isum;
#pragma unroll
        for (int c = 0; c < 8; ++c) o[c] = fmaf(e[s][c], b, o[c]);
    }
    float4 ova, ovb;
    ova.x = fmaxf(o[0], 0.f); ova.y = fmaxf(o[1], 0.f);
    ova.z = fmaxf(o[2], 0.f); ova.w = fmaxf(o[3], 0.f);
    ovb.x = fmaxf(o[4], 0.f); ovb.y = fmaxf(o[5], 0.f);
    ovb.z = fmaxf(o[6], 0.f); ovb.w = fmaxf(o[7], 0.f);
    *reinterpret_cast<float4*>(out + (size_t)n * D_OUTF + c8)     = ova;
    *reinterpret_cast<float4*>(out + (size_t)n * D_OUTF + c8 + 4) = ovb;
}

// ---------------------------------------------------------------------------
extern "C" void kernel_launch(void* const* d_in, const int* in_sizes, int n_in,
                              void* d_out, int out_size, void* d_ws, size_t ws_size,
                              hipStream_t stream)
{
    const float* x     = (const float*)d_in[0];
    const int*   ei    = (const int*)  d_in[1];
    const float* Wl    = (const float*)d_in[2];
    const float* bl    = (const float*)d_in[3];
    const float* Wr    = (const float*)d_in[4];
    const float* br    = (const float*)d_in[5];
    const float* attn  = (const float*)d_in[6];
    const float* ral   = (const float*)d_in[7];
    const float* rar   = (const float*)d_in[8];
    const float* rbias = (const float*)d_in[9];
    float* out = (float*)d_out;

    char* ws = (char*)d_ws;
    size_t off = 0;
    float* rbuf   = (float*)(ws + off); off += (size_t)N_NODES * D_OUTF * 4;    // 51.2 MB
    float* alr    = (float*)(ws + off); off += (size_t)3 * N_NODES * 4 * 4;     // 4.8 MB
    float* ar     = (float*)(ws + off); off += (size_t)N_NODES * 12 * 4;        // 4.8 MB
    int*   deg    = (int*)  (ws + off); off += (size_t)3 * N_NODES * 4;         // 1.2 MB
    int*   rowst  = (int*)  (ws + off); off += (size_t)3 * N_NODES * 4;         // 1.2 MB
    int*   colall = (int*)  (ws + off); off += (size_t)TOT_E * 4;               // 7.2 MB
    int*   bcnt   = (int*)  (ws + off); off += (size_t)256 * 4;
    unsigned short* wt  = (unsigned short*)(ws + off); off += (size_t)2 * 2 * 128 * 256 * 2; // 256 KB
    unsigned short* lbf = (unsigned short*)(ws + off); off += (size_t)N_NODES * D_OUTF * 2;  // 25.6 MB
    uint2* gstage = (uint2*)(ws + off); off += (size_t)NBUCKT * CAPB * 8;       // 19.3 MB

    hipMemsetAsync(bcnt, 0, (size_t)NBUCKT * 4, stream);

    part_wt<<<256 + NPART_BLOCKS, 256, 0, stream>>>(Wl, Wr, wt, ei, bcnt, gstage);

    // fused: proj (8-wave, x staged once, no spill) ∥ bucket scatter + CSR
    proj_scatter<<<NTOT_BLOCKS, 512, 0, stream>>>(
        x, wt, bl, br, attn, rbuf, alr, ar, lbf, gstage, bcnt,
        deg, rowst, colall);

    aggregate_kernel<<<N_NODES / 16, 256, 0, stream>>>(
        (const uint4*)lbf, rbuf, alr, ar, rowst, deg, colall,
        ral, rar, rbias, out);
}

// Round 24
// 257.128 us; speedup vs baseline: 1.1236x; 1.0737x over previous
//
#include <hip/hip_runtime.h>
#include <hip/hip_bf16.h>

#define N_NODES 100000
#define N_EDGES 600000
#define N_REL   3
#define D_INF   256
#define D_OUTF  128
#define TOT_E   (3 * N_EDGES)

#define NB_REL   49                              // dst>>11 -> 0..48
#define NBUCKT   (3 * NB_REL)                    // 147
#define CAPB     16384                           // staging capacity per bucket

#define NPART_BLOCKS ((TOT_E + 4095) / 4096)     // 440

#define NPROJ_BLOCKS (((N_NODES + 63) / 64) * 2)        // 3126
#define NTOT_BLOCKS  (NPROJ_BLOCKS + NBUCKT)            // 3273

typedef __attribute__((ext_vector_type(8))) short          bf16x8;
typedef __attribute__((ext_vector_type(8))) unsigned short ushort8;
typedef __attribute__((ext_vector_type(4))) float          f32x4;

#define LPAD 72
#define LTS  136

__device__ __forceinline__ unsigned short bf16_rne(float v) {
    unsigned int b = __float_as_uint(v);
    b += 0x7FFFu + ((b >> 16) & 1u);
    return (unsigned short)(b >> 16);
}

// ---------------------------------------------------------------------------
// K0 (FUSED): wt_prep (blocks 0..255) + bucket partition (440 blocks).
// ---------------------------------------------------------------------------
__global__ __launch_bounds__(256) void part_wt(
    const float* __restrict__ Wl, const float* __restrict__ Wr,
    unsigned short* __restrict__ wt,
    const int* __restrict__ ei, int* __restrict__ bcnt,
    uint2* __restrict__ gstage)
{
    const int bid = blockIdx.x;
    const int t   = threadIdx.x;
    if (bid < 256) {
        const int k = bid;
        const int w = t >> 7;
        const int n = t & 127;
        const float v = (w ? Wr : Wl)[(size_t)k * D_OUTF + n];
        const unsigned short h = bf16_rne(v);
        const float fhi = __uint_as_float(((unsigned int)h) << 16);
        const unsigned short g = bf16_rne(v - fhi);
        const int kb   = k >> 6;
        const int kk   = (k >> 5) & 1;
        const int lgrp = (k >> 3) & 3;
        const int j    = k & 7;
        const int cf   = n >> 4;
        const int lane = lgrp * 16 + (n & 15);
        const size_t fh = ((((size_t)(w * 2 + 0) * 4 + kb) * 2 + kk) * 8 + cf) * 512 + lane * 8 + j;
        const size_t fl = ((((size_t)(w * 2 + 1) * 4 + kb) * 2 + kk) * 8 + cf) * 512 + lane * 8 + j;
        wt[fh] = h;
        wt[fl] = g;
        return;
    }
    __shared__ int lh[NBUCKT];
    __shared__ int lc[NBUCKT];
    const int base = (bid - 256) * 4096;

    for (int q = t; q < NBUCKT; q += 256) lh[q] = 0;
    __syncthreads();
#pragma unroll
    for (int r = 0; r < 16; ++r) {
        const int ge = base + r * 256 + t;
        if (ge < TOT_E) {
            const int rr = (ge >= 2 * N_EDGES) ? 2 : ((ge >= N_EDGES) ? 1 : 0);
            const int e  = ge - rr * N_EDGES;
            const int dst = ei[(size_t)rr * 2 * N_EDGES + N_EDGES + e];
            atomicAdd(&lh[rr * NB_REL + (dst >> 11)], 1);
        }
    }
    __syncthreads();
    for (int q = t; q < NBUCKT; q += 256)
        lc[q] = lh[q] ? atomicAdd(&bcnt[q], lh[q]) : 0;
    __syncthreads();
#pragma unroll
    for (int r = 0; r < 16; ++r) {
        const int ge = base + r * 256 + t;
        if (ge < TOT_E) {
            const int rr = (ge >= 2 * N_EDGES) ? 2 : ((ge >= N_EDGES) ? 1 : 0);
            const int e  = ge - rr * N_EDGES;
            const int src = ei[(size_t)rr * 2 * N_EDGES + e];
            const int dst = ei[(size_t)rr * 2 * N_EDGES + N_EDGES + e];
            const int qb  = rr * NB_REL + (dst >> 11);
            const int off = atomicAdd(&lc[qb], 1);
            uint2 u; u.x = (unsigned)src; u.y = (unsigned)(dst | (rr << 20));
            gstage[(size_t)qb * CAPB + off] = u;
        }
    }
}

// ---------------------------------------------------------------------------
// K1 (FUSED): proj GEMM (single-buffered x staging, VGPR~40, ~6 blocks/CU)
// ∥ bucket scatter+CSR-build (gb computed in-block).
// ---------------------------------------------------------------------------
__global__ __launch_bounds__(256, 6) void proj_scatter(
    const float* __restrict__ x, const unsigned short* __restrict__ wt,
    const float* __restrict__ bl, const float* __restrict__ br,
    const float* __restrict__ attn,
    float* __restrict__ rbuf,
    float* __restrict__ alr,  float* __restrict__ ar,
    unsigned short* __restrict__ lbf,
    const uint2* __restrict__ gstage, const int* __restrict__ bcnt,
    int* __restrict__ deg, int* __restrict__ rowst, int* __restrict__ colall)
{
    __shared__ unsigned short smem[2 * 64 * LPAD];   // 18432 B
    __shared__ int wsum2[4];
    __shared__ int wexcl2[4];

    const int bid = blockIdx.x;
    const unsigned int pb = (unsigned int)(((unsigned long long)bid * NPROJ_BLOCKS) / NTOT_BLOCKS);
    const unsigned int pa = (unsigned int)(((unsigned long long)(bid + 1) * NPROJ_BLOCKS) / NTOT_BLOCKS);

    if (pa == pb) {
        // ============ bucket scatter + CSR build ============
        const int b     = bid - (int)pb;          // 0..146
        const int rrb   = b / NB_REL;
        const int node0 = (b % NB_REL) * 2048;
        const int nN    = min(2048, N_NODES - node0);
        const int t     = threadIdx.x;
        int* hist = (int*)smem;                   // 2048 ints
        const int cnt_b = bcnt[b];
        const size_t sbase = (size_t)b * CAPB;

        // gb = exclusive prefix of bcnt at b (256-thread reduce)
        {
            int pv = (t < b) ? bcnt[t] : 0;       // b <= 146 < 256
#pragma unroll
            for (int m = 32; m >= 1; m >>= 1) pv += __shfl_xor(pv, m);
            if ((t & 63) == 0) wsum2[t >> 6] = pv;
        }
        for (int q = t; q < 2048; q += 256) hist[q] = 0;
        __syncthreads();
        const int gb = wsum2[0] + wsum2[1] + wsum2[2] + wsum2[3];

        for (int e = t; e < cnt_b; e += 256) {
            const uint2 u = gstage[sbase + e];
            atomicAdd(&hist[(int)(u.y & 0xFFFFFu) - node0], 1);
        }
        __syncthreads();
        for (int q = t; q < nN; q += 256)
            deg[rrb * N_NODES + node0 + q] = hist[q];
        __syncthreads();
        {
            const int lane = t & 63;
            const int wid  = t >> 6;
            int v[8]; int tsum = 0;
#pragma unroll
            for (int i = 0; i < 8; ++i) { v[i] = hist[t * 8 + i]; tsum += v[i]; }
            int inc = tsum;
#pragma unroll
            for (int off2 = 1; off2 < 64; off2 <<= 1) {
                const int u2 = __shfl_up(inc, off2);
                if (lane >= off2) inc += u2;
            }
            if (lane == 63) wsum2[wid] = inc;
            __syncthreads();
            if (t == 0) {
                int s = 0;
#pragma unroll
                for (int i2 = 0; i2 < 4; ++i2) { const int tv = wsum2[i2]; wexcl2[i2] = s; s += tv; }
            }
            __syncthreads();
            int run = gb + wexcl2[wid] + (inc - tsum);
#pragma unroll
            for (int i = 0; i < 8; ++i) {
                const int q = t * 8 + i;
                const int st = run;
                run += v[i];
                hist[q] = st;
                if (q < nN) rowst[rrb * N_NODES + node0 + q] = st;
            }
        }
        __syncthreads();
        for (int e = t; e < cnt_b; e += 256) {
            const uint2 u = gstage[sbase + e];
            const int loc = (int)(u.y & 0xFFFFFu) - node0;
            const int pos = atomicAdd(&hist[loc], 1);
            colall[pos] = (int)u.x;
        }
        return;
    }

    // ================= proj block #pb =================
    const int tid  = threadIdx.x;
    const int nb   = (int)(pb >> 1) * 64;
    const int w    = (int)(pb & 1);

    const int lane = tid & 63;
    const int wv   = tid >> 6;      // wave 0..3
    const int rowf = lane & 15;
    const int kgrp = lane >> 4;     // 0..3

    f32x4 acc[8];
#pragma unroll
    for (int cf = 0; cf < 8; ++cf) acc[cf] = (f32x4){0.f, 0.f, 0.f, 0.f};

    for (int kb4 = 0; kb4 < 4; ++kb4) {
        __syncthreads();
        {
            const int r   = tid >> 2;
            const int seg = tid & 3;
            int rowg = nb + r; if (rowg >= N_NODES) rowg = N_NODES - 1;
            const float* src = x + (size_t)rowg * D_INF + kb4 * 64 + seg * 16;
#pragma unroll
            for (int q2 = 0; q2 < 2; ++q2) {
                const float4 v0 = *reinterpret_cast<const float4*>(src + q2 * 8);
                const float4 v1 = *reinterpret_cast<const float4*>(src + q2 * 8 + 4);
                const float vv[8] = {v0.x, v0.y, v0.z, v0.w, v1.x, v1.y, v1.z, v1.w};
                ushort8 hv, gv;
#pragma unroll
                for (int q = 0; q < 8; ++q) {
                    const unsigned short h = bf16_rne(vv[q]);
                    hv[q] = h;
                    const float fhi = __uint_as_float(((unsigned int)h) << 16);
                    gv[q] = bf16_rne(vv[q] - fhi);
                }
                *reinterpret_cast<ushort8*>(&smem[0 * 64 * LPAD + r * LPAD + seg * 16 + q2 * 8]) = hv;
                *reinterpret_cast<ushort8*>(&smem[1 * 64 * LPAD + r * LPAD + seg * 16 + q2 * 8]) = gv;
            }
        }
        __syncthreads();

#pragma unroll
        for (int kk = 0; kk < 2; ++kk) {
            const int ko = kk * 32 + kgrp * 8;
            const bf16x8 ahi = *reinterpret_cast<const bf16x8*>(&smem[0 * 64 * LPAD + (wv * 16 + rowf) * LPAD + ko]);
            const bf16x8 alo = *reinterpret_cast<const bf16x8*>(&smem[1 * 64 * LPAD + (wv * 16 + rowf) * LPAD + ko]);
#pragma unroll
            for (int cf = 0; cf < 8; ++cf) {
                const bf16x8 bhi = *reinterpret_cast<const bf16x8*>(
                    wt + ((((size_t)(w * 2 + 0) * 4 + kb4) * 2 + kk) * 8 + cf) * 512 + lane * 8);
                const bf16x8 blo = *reinterpret_cast<const bf16x8*>(
                    wt + ((((size_t)(w * 2 + 1) * 4 + kb4) * 2 + kk) * 8 + cf) * 512 + lane * 8);
                acc[cf] = __builtin_amdgcn_mfma_f32_16x16x32_bf16(ahi, bhi, acc[cf], 0, 0, 0);
                acc[cf] = __builtin_amdgcn_mfma_f32_16x16x32_bf16(ahi, blo, acc[cf], 0, 0, 0);
                acc[cf] = __builtin_amdgcn_mfma_f32_16x16x32_bf16(alo, bhi, acc[cf], 0, 0, 0);
            }
        }
    }
    __syncthreads();   // xs reads done; safe to reuse smem in phase 2

    // ==== phase 2: relu + outputs ====
    float o_[8][4];
    {
        const float* bias = w ? br : bl;
#pragma unroll
        for (int cf = 0; cf < 8; ++cf) {
            const float bvv = bias[cf * 16 + rowf];
#pragma unroll
            for (int j = 0; j < 4; ++j)
                o_[cf][j] = fmaxf(acc[cf][j] + bvv, 0.f);
        }
    }

    if (w == 1) {
#pragma unroll
        for (int cf = 0; cf < 8; ++cf)
#pragma unroll
            for (int j = 0; j < 4; ++j) {
                const int node = nb + wv * 16 + kgrp * 4 + j;
                if (node < N_NODES)
                    rbuf[(size_t)node * D_OUTF + cf * 16 + rowf] = o_[cf][j];
            }
    }

    // al/ar: f32 dot with attn band + 16-lane shfl reduce (over rowf)
    {
        const int woff = w ? 32 : 0;
#pragma unroll
        for (int rr = 0; rr < 3; ++rr) {
            float pr[4][4];
#pragma unroll
            for (int hh = 0; hh < 4; ++hh) {
                const float A0 = attn[rr * 256 + hh * 64 + woff + rowf];
                const float A1 = attn[rr * 256 + hh * 64 + woff + 16 + rowf];
#pragma unroll
                for (int j = 0; j < 4; ++j)
                    pr[hh][j] = fmaf(o_[2 * hh][j], A0, o_[2 * hh + 1][j] * A1);
            }
#pragma unroll
            for (int hh = 0; hh < 4; ++hh)
#pragma unroll
                for (int j = 0; j < 4; ++j) {
#pragma unroll
                    for (int m = 8; m >= 1; m >>= 1)
                        pr[hh][j] += __shfl_xor(pr[hh][j], m);
                }
            if ((rowf >> 2) == rr) {
#pragma unroll
                for (int j = 0; j < 4; ++j) {
                    float v = pr[0][j];
#pragma unroll
                    for (int hh = 1; hh < 4; ++hh)
                        if ((rowf & 3) == hh) v = pr[hh][j];
                    const int node = nb + wv * 16 + kgrp * 4 + j;
                    if (node < N_NODES) {
                        if (w == 0)
                            alr[((size_t)rr * N_NODES + node) * 4 + (rowf & 3)] = v;
                        else
                            ar[(size_t)node * 12 + rowf] = v;
                    }
                }
            }
        }
    }

    // lbf (bf16 l copy) via smem staging, coalesced  (w==0 only)
    if (w == 0) {
#pragma unroll
        for (int cf = 0; cf < 8; ++cf)
#pragma unroll
            for (int j = 0; j < 4; ++j)
                smem[(wv * 16 + kgrp * 4 + j) * LTS + cf * 16 + rowf] = bf16_rne(o_[cf][j]);
        __syncthreads();
#pragma unroll
        for (int q = 0; q < 4; ++q) {
            const int idx = tid + q * 256;
            const int r2  = idx >> 4;
            const int c8  = (idx & 15) * 8;
            const int node = nb + r2;
            if (node < N_NODES)
                *reinterpret_cast<ushort8*>(&lbf[(size_t)node * D_OUTF + c8]) =
                    *reinterpret_cast<ushort8*>(&smem[r2 * LTS + c8]);
        }
    }
}

// ---------------------------------------------------------------------------
// K2: aggregation v6 (4 nodes/wave, 16 lanes x 8 ch, per-group bounds).
// ---------------------------------------------------------------------------
__global__ __launch_bounds__(256) void aggregate_kernel(
    const uint4* __restrict__ lbf128, const float* __restrict__ rbuf,
    const float* __restrict__ alr,  const float* __restrict__ ar,
    const int* __restrict__ rowst,  const int* __restrict__ deg,
    const int* __restrict__ colall,
    const float* __restrict__ rel_attn_l, const float* __restrict__ rel_attn_r,
    const float* __restrict__ rel_bias,   float* __restrict__ out)
{
    __shared__ int   src_sh[4][4][3][16];        // 3 KB
    __shared__ float w_sh[4][4][3][16][4];       // 12 KB

    const int wv   = threadIdx.x >> 6;
    const int lane = threadIdx.x & 63;
    const int g    = lane >> 4;          // node slot 0..3
    const int j    = lane & 15;          // lane within group
    const int n    = blockIdx.x * 16 + wv * 4 + g;

    const int h  = j >> 2;               // head 0..3 (4 lanes per head)
    const int c8 = j * 8;                // first of 8 owned channels

    int   start_[3], cnt_[3], cm_[3], base_[3];
    float4 ar4_[3];
#pragma unroll
    for (int rr = 0; rr < 3; ++rr) {
        start_[rr] = rowst[rr * N_NODES + n];
        cnt_[rr]   = deg[rr * N_NODES + n];
        ar4_[rr]   = *reinterpret_cast<const float4*>(ar + (size_t)n * 12 + rr * 4);
        int cm = cnt_[rr];
        cm = max(cm, __shfl_xor(cm, 16));
        cm = max(cm, __shfl_xor(cm, 32));
        cm_[rr] = cm;                    // wave-uniform
        base_[rr] = 0;
    }

    float ex[3][8];
    float den[3];
#pragma unroll
    for (int rr = 0; rr < 3; ++rr) {
        den[rr] = 0.f;
#pragma unroll
        for (int c = 0; c < 8; ++c) ex[rr][c] = 0.f;
    }

    while (base_[0] < cm_[0] || base_[1] < cm_[1] || base_[2] < cm_[2]) {
        int mm_[3];
        int mxw_[3];
#pragma unroll
        for (int rr = 0; rr < 3; ++rr) {
            mm_[rr] = 0; mxw_[rr] = 0;
            if (base_[rr] < cm_[rr]) {
                mm_[rr]  = min(16, max(0, cnt_[rr] - base_[rr]));
                mxw_[rr] = min(16, cm_[rr] - base_[rr]);
                const int sj = (j < mm_[rr]) ? colall[start_[rr] + base_[rr] + j] : 0;
                const float4 al4 = *reinterpret_cast<const float4*>(
                    alr + ((size_t)rr * N_NODES + sj) * 4);
                float t0 = al4.x + ar4_[rr].x, t1 = al4.y + ar4_[rr].y;
                float t2 = al4.z + ar4_[rr].z, t3 = al4.w + ar4_[rr].w;
                t0 = fmaxf(t0, 0.2f * t0); t1 = fmaxf(t1, 0.2f * t1);
                t2 = fmaxf(t2, 0.2f * t2); t3 = fmaxf(t3, 0.2f * t3);
                float e0 = __expf(t0), e1 = __expf(t1);
                float e2 = __expf(t2), e3 = __expf(t3);
                if (j >= mm_[rr]) { e0 = 0.f; e1 = 0.f; e2 = 0.f; e3 = 0.f; }
                src_sh[wv][g][rr][j] = sj;
                f32x4 w4; w4[0] = e0; w4[1] = e1; w4[2] = e2; w4[3] = e3;
                *reinterpret_cast<f32x4*>(&w_sh[wv][g][rr][j][0]) = w4;
            }
        }
        const int mxall = max(mxw_[0], max(mxw_[1], mxw_[2]));
        for (int i = 0; i < mxall; ++i) {
#pragma unroll
            for (int rr = 0; rr < 3; ++rr) {
                if (i < mm_[rr]) {
                    const int   srcI = src_sh[wv][g][rr][i];
                    const float wsel = w_sh[wv][g][rr][i][h];
                    const uint4 u = lbf128[(size_t)srcI * 16 + j];
                    den[rr] += wsel;
                    ex[rr][0] = fmaf(wsel, __uint_as_float(u.x << 16),         ex[rr][0]);
                    ex[rr][1] = fmaf(wsel, __uint_as_float(u.x & 0xFFFF0000u), ex[rr][1]);
                    ex[rr][2] = fmaf(wsel, __uint_as_float(u.y << 16),         ex[rr][2]);
                    ex[rr][3] = fmaf(wsel, __uint_as_float(u.y & 0xFFFF0000u), ex[rr][3]);
                    ex[rr][4] = fmaf(wsel, __uint_as_float(u.z << 16),         ex[rr][4]);
                    ex[rr][5] = fmaf(wsel, __uint_as_float(u.z & 0xFFFF0000u), ex[rr][5]);
                    ex[rr][6] = fmaf(wsel, __uint_as_float(u.w << 16),         ex[rr][6]);
                    ex[rr][7] = fmaf(wsel, __uint_as_float(u.w & 0xFFFF0000u), ex[rr][7]);
                }
            }
        }
#pragma unroll
        for (int rr = 0; rr < 3; ++rr) base_[rr] += 16;
    }

    float e[4][8];
#pragma unroll
    for (int rr = 0; rr < 3; ++rr) {
        const float inv = 1.f / (den[rr] + 1e-16f);
#pragma unroll
        for (int c = 0; c < 8; ++c) e[rr][c] = ex[rr][c] * inv;
    }
    {
        const uint4 u = lbf128[(size_t)n * 16 + j];
        e[3][0] = __uint_as_float(u.x << 16);
        e[3][1] = __uint_as_float(u.x & 0xFFFF0000u);
        e[3][2] = __uint_as_float(u.y << 16);
        e[3][3] = __uint_as_float(u.y & 0xFFFF0000u);
        e[3][4] = __uint_as_float(u.z << 16);
        e[3][5] = __uint_as_float(u.z & 0xFFFF0000u);
        e[3][6] = __uint_as_float(u.w << 16);
        e[3][7] = __uint_as_float(u.w & 0xFFFF0000u);
    }

    float blc[8];
    {
        const float4 rva = *reinterpret_cast<const float4*>(rbuf + (size_t)n * D_OUTF + c8);
        const float4 rvb = *reinterpret_cast<const float4*>(rbuf + (size_t)n * D_OUTF + c8 + 4);
        const float4 rla = *reinterpret_cast<const float4*>(rel_attn_l + c8);
        const float4 rlb = *reinterpret_cast<const float4*>(rel_attn_l + c8 + 4);
        blc[0] = fmaxf(rva.x * rla.x, 0.f);
        blc[1] = fmaxf(rva.y * rla.y, 0.f);
        blc[2] = fmaxf(rva.z * rla.z, 0.f);
        blc[3] = fmaxf(rva.w * rla.w, 0.f);
        blc[4] = fmaxf(rvb.x * rlb.x, 0.f);
        blc[5] = fmaxf(rvb.y * rlb.y, 0.f);
        blc[6] = fmaxf(rvb.z * rlb.z, 0.f);
        blc[7] = fmaxf(rvb.w * rlb.w, 0.f);
    }

    float beta[4];
#pragma unroll
    for (int s = 0; s < 4; ++s) {
        const float4 ra = *reinterpret_cast<const float4*>(rel_attn_r + s * D_OUTF + c8);
        const float4 rb = *reinterpret_cast<const float4*>(rel_attn_r + s * D_OUTF + c8 + 4);
        float p = 0.f;
        p = fmaf(blc[0], fmaxf(e[s][0] * ra.x, 0.f), p);
        p = fmaf(blc[1], fmaxf(e[s][1] * ra.y, 0.f), p);
        p = fmaf(blc[2], fmaxf(e[s][2] * ra.z, 0.f), p);
        p = fmaf(blc[3], fmaxf(e[s][3] * ra.w, 0.f), p);
        p = fmaf(blc[4], fmaxf(e[s][4] * rb.x, 0.f), p);
        p = fmaf(blc[5], fmaxf(e[s][5] * rb.y, 0.f), p);
        p = fmaf(blc[6], fmaxf(e[s][6] * rb.z, 0.f), p);
        p = fmaf(blc[7], fmaxf(e[s][7] * rb.w, 0.f), p);
        p += __shfl_xor(p, 2);
        p += __shfl_xor(p, 1);
        beta[s] = p + rel_bias[s];
    }

    const float mx2 = fmaxf(fmaxf(beta[0], beta[1]), fmaxf(beta[2], beta[3]));
    float ssum = 0.f;
#pragma unroll
    for (int s = 0; s < 4; ++s) { beta[s] = __expf(beta[s] - mx2); ssum += beta[s]; }
    const float isum = 1.f / ssum;
    float o[8];
#pragma unroll
    for (int c = 0; c < 8; ++c) o[c] = 0.f;
#pragma unroll
    for (int s = 0; s < 4; ++s) {
        const float b = beta[s] * isum;
#pragma unroll
        for (int c = 0; c < 8; ++c) o[c] = fmaf(e[s][c], b, o[c]);
    }
    float4 ova, ovb;
    ova.x = fmaxf(o[0], 0.f); ova.y = fmaxf(o[1], 0.f);
    ova.z = fmaxf(o[2], 0.f); ova.w = fmaxf(o[3], 0.f);
    ovb.x = fmaxf(o[4], 0.f); ovb.y = fmaxf(o[5], 0.f);
    ovb.z = fmaxf(o[6], 0.f); ovb.w = fmaxf(o[7], 0.f);
    *reinterpret_cast<float4*>(out + (size_t)n * D_OUTF + c8)     = ova;
    *reinterpret_cast<float4*>(out + (size_t)n * D_OUTF + c8 + 4) = ovb;
}

// ---------------------------------------------------------------------------
extern "C" void kernel_launch(void* const* d_in, const int* in_sizes, int n_in,
                              void* d_out, int out_size, void* d_ws, size_t ws_size,
                              hipStream_t stream)
{
    const float* x     = (const float*)d_in[0];
    const int*   ei    = (const int*)  d_in[1];
    const float* Wl    = (const float*)d_in[2];
    const float* bl    = (const float*)d_in[3];
    const float* Wr    = (const float*)d_in[4];
    const float* br    = (const float*)d_in[5];
    const float* attn  = (const float*)d_in[6];
    const float* ral   = (const float*)d_in[7];
    const float* rar   = (const float*)d_in[8];
    const float* rbias = (const float*)d_in[9];
    float* out = (float*)d_out;

    char* ws = (char*)d_ws;
    size_t off = 0;
    float* rbuf   = (float*)(ws + off); off += (size_t)N_NODES * D_OUTF * 4;    // 51.2 MB
    float* alr    = (float*)(ws + off); off += (size_t)3 * N_NODES * 4 * 4;     // 4.8 MB
    float* ar     = (float*)(ws + off); off += (size_t)N_NODES * 12 * 4;        // 4.8 MB
    int*   deg    = (int*)  (ws + off); off += (size_t)3 * N_NODES * 4;         // 1.2 MB
    int*   rowst  = (int*)  (ws + off); off += (size_t)3 * N_NODES * 4;         // 1.2 MB
    int*   colall = (int*)  (ws + off); off += (size_t)TOT_E * 4;               // 7.2 MB
    int*   bcnt   = (int*)  (ws + off); off += (size_t)256 * 4;
    unsigned short* wt  = (unsigned short*)(ws + off); off += (size_t)2 * 2 * 128 * 256 * 2; // 256 KB
    unsigned short* lbf = (unsigned short*)(ws + off); off += (size_t)N_NODES * D_OUTF * 2;  // 25.6 MB
    uint2* gstage = (uint2*)(ws + off); off += (size_t)NBUCKT * CAPB * 8;       // 19.3 MB

    hipMemsetAsync(bcnt, 0, (size_t)NBUCKT * 4, stream);

    part_wt<<<256 + NPART_BLOCKS, 256, 0, stream>>>(Wl, Wr, wt, ei, bcnt, gstage);

    // fused: proj (single-buffered, occ-6) ∥ bucket scatter + CSR build
    proj_scatter<<<NTOT_BLOCKS, 256, 0, stream>>>(
        x, wt, bl, br, attn, rbuf, alr, ar, lbf, gstage, bcnt,
        deg, rowst, colall);

    aggregate_kernel<<<N_NODES / 16, 256, 0, stream>>>(
        (const uint4*)lbf, rbuf, alr, ar, rowst, deg, colall,
        ral, rar, rbias, out);
}